// Round 7
// baseline (1353.398 us; speedup 1.0000x reference)
//
#include <hip/hip_runtime.h>
#include <hip/hip_bf16.h>
#include <stdint.h>

typedef __hip_bfloat16 bf16;
typedef __attribute__((ext_vector_type(8))) short short8;
typedef __attribute__((ext_vector_type(4))) float f32x4;

#define NN 200000    // nodes
#define NNPAD 200064 // 1563*128
#define NE 400000    // directed edges
#define DV 133
#define DE 14
#define DH 200
#define MT 128       // M rows per block
#define NT 13        // 13 col tiles of 16 (200 -> 208 padded)
#define NCH 782      // ceil(NN/256) scan chunks

#define CI 5         // K chunks Wi (147 -> 160)
#define CH 7         // K chunks Wh (200 -> 224)
#define CO 11        // K chunks Wo (333 -> 352)
#define KO 352
#define LDV 160      // Vb16 row stride (shorts)

#define MFMA(a, b, c) __builtin_amdgcn_mfma_f32_16x16x32_bf16((a), (b), (c), 0, 0, 0)

__device__ __forceinline__ float us2f(unsigned short u) {
  return __uint_as_float(((unsigned)u) << 16);
}
__device__ __forceinline__ unsigned short f2us(float f) {
  bf16 h = __float2bfloat16(f);
  return *reinterpret_cast<unsigned short*>(&h);
}

// ---- W pack into MFMA-fragment order --------------------------------------
__global__ __launch_bounds__(256) void prepwpack_kernel(
    const float* __restrict__ W, int Ksrc, int nchunks, int mode,
    unsigned short* __restrict__ out)
{
  int f = blockIdx.x * 256 + threadIdx.x;
  int total = nchunks * 13 * 64;
  if (f >= total) return;
  int c = f / 832, rem = f - c * 832;
  int t = rem >> 6, l = rem & 63;
  int q = l >> 4, ln = l & 15;
  int col = t * 16 + ln;
  short8 w;
#pragma unroll
  for (int j = 0; j < 8; ++j) {
    int k = c * 32 + q * 8 + j;
    float v = 0.f;
    if (col < DH) {
      if (mode == 0) {
        if (k < Ksrc) v = W[(size_t)k * DH + col];
      } else {
        if (k < 333) {
          int sr = (k < 200) ? (133 + k) : (k - 200);
          v = W[(size_t)sr * DH + col];
        }
      }
    }
    w[j] = (short)f2us(v);
  }
  *(short8*)&out[(size_t)f * 8] = w;
}

// -------- V -> bf16, padded row stride LDV (cols >= DV zero) -----------------
__global__ __launch_bounds__(256) void packv_kernel(
    const float* __restrict__ V, unsigned short* __restrict__ Vb)
{
  int idx = blockIdx.x * 256 + threadIdx.x;   // one short8 per thread
  if (idx >= NN * (LDV / 8)) return;
  int n = idx / (LDV / 8), g = idx - n * (LDV / 8);
  int k0 = g * 8;
  short8 w;
#pragma unroll
  for (int j = 0; j < 8; ++j) {
    int k = k0 + j;
    float v = (k < DV) ? V[(size_t)n * DV + k] : 0.f;
    w[j] = (short)f2us(v);
  }
  *(short8*)&Vb[(size_t)n * LDV + k0] = w;
}

// ---- per-position tail for h0 chunk 4: Et[p][0..31] = k 128..159 of
// [V[src[perm[p]]] || Ef[perm[p]]]
__global__ __launch_bounds__(256) void packet_kernel(
    const float* __restrict__ V, const float* __restrict__ Ef,
    const int* __restrict__ perm, const int* __restrict__ psrc,
    unsigned short* __restrict__ Et)
{
  int idx = blockIdx.x * 256 + threadIdx.x;
  if (idx >= NE * 4) return;
  int p = idx >> 2, part = idx & 3;
  int e = perm[p];
  short8 w;
#pragma unroll
  for (int j = 0; j < 8; ++j) w[j] = 0;
  if (part == 0) {
    int s = psrc[p];
#pragma unroll
    for (int j = 0; j < 5; ++j) w[j] = (short)f2us(V[(size_t)s * DV + 128 + j]);
#pragma unroll
    for (int j = 5; j < 8; ++j) w[j] = (short)f2us(Ef[(size_t)e * DE + (j - 5)]);
  } else if (part == 1) {
#pragma unroll
    for (int j = 0; j < 8; ++j) w[j] = (short)f2us(Ef[(size_t)e * DE + 3 + j]);
  } else if (part == 2) {
#pragma unroll
    for (int j = 0; j < 3; ++j) w[j] = (short)f2us(Ef[(size_t)e * DE + 11 + j]);
  }
  *(short8*)&Et[(size_t)p * 32 + part * 8] = w;
}

// ---- fill Abuf cols 200..351 with bf16(V), zero pad; zero rows >= NN --------
__global__ __launch_bounds__(256) void packav_kernel(
    const float* __restrict__ V, unsigned short* __restrict__ Abuf)
{
  int idx = blockIdx.x * 256 + threadIdx.x;   // one short8 per thread
  if (idx >= NNPAD * (KO / 8)) return;
  int n = idx / (KO / 8), g = idx - n * (KO / 8);
  int k0 = g * 8;
  if (n < NN && k0 < 200) return;             // gather owns these
  short8 w;
#pragma unroll
  for (int j = 0; j < 8; ++j) {
    int k = k0 + j;
    float v = (n < NN && k >= 200 && k < 333) ? V[(size_t)n * DV + (k - 200)] : 0.f;
    w[j] = (short)f2us(v);
  }
  *(short8*)&Abuf[(size_t)n * KO + k0] = w;
}

// ---------------- CSR build: hist -> scan -> scatter --------------------------
__global__ __launch_bounds__(256) void hist_kernel(
    const int* __restrict__ dst, int* __restrict__ counts)
{
  int e = blockIdx.x * 256 + threadIdx.x;
  if (e < NE) atomicAdd(&counts[dst[e]], 1);
}

__global__ __launch_bounds__(256) void chunksum_kernel(
    const int* __restrict__ counts, int* __restrict__ chunkSum)
{
  int b = blockIdx.x, tid = threadIdx.x;
  int i = b * 256 + tid;
  int v = (i < NN) ? counts[i] : 0;
#pragma unroll
  for (int d = 32; d; d >>= 1) v += __shfl_down(v, d, 64);
  __shared__ int ws[4];
  if ((tid & 63) == 0) ws[tid >> 6] = v;
  __syncthreads();
  if (tid == 0) chunkSum[b] = ws[0] + ws[1] + ws[2] + ws[3];
}

__global__ __launch_bounds__(1024) void scanchunks_kernel(
    const int* __restrict__ chunkSum, int* __restrict__ chunkOff)
{
  __shared__ int s[1024];
  int tid = threadIdx.x;
  int v = (tid < NCH) ? chunkSum[tid] : 0;
  s[tid] = v;
  __syncthreads();
  for (int d = 1; d < 1024; d <<= 1) {
    int t = (tid >= d) ? s[tid - d] : 0;
    __syncthreads();
    s[tid] += t;
    __syncthreads();
  }
  if (tid < NCH) chunkOff[tid] = s[tid] - v;  // exclusive
}

__global__ __launch_bounds__(256) void scanlocal_kernel(
    const int* __restrict__ counts, const int* __restrict__ chunkOff,
    int* __restrict__ offsets, int* __restrict__ cursor)
{
  __shared__ int s[256];
  int b = blockIdx.x, tid = threadIdx.x;
  int i = b * 256 + tid;
  int v = (i < NN) ? counts[i] : 0;
  s[tid] = v;
  __syncthreads();
  for (int d = 1; d < 256; d <<= 1) {
    int t = (tid >= d) ? s[tid - d] : 0;
    __syncthreads();
    s[tid] += t;
    __syncthreads();
  }
  if (i < NN) {
    int off = chunkOff[b] + s[tid] - v;
    offsets[i] = off;
    cursor[i] = off;
  }
  if (i == 0) offsets[NN] = NE;
}

__global__ __launch_bounds__(256) void scatter_kernel(
    const int* __restrict__ dst, int* __restrict__ cursor, int* __restrict__ perm)
{
  int e = blockIdx.x * 256 + threadIdx.x;
  if (e < NE) {
    int p = atomicAdd(&cursor[dst[e]], 1);
    perm[p] = e;
  }
}

// ---- ipos[perm[p]] = p ------------------------------------------------------
__global__ __launch_bounds__(256) void invperm_kernel(
    const int* __restrict__ perm, int* __restrict__ ipos)
{
  int p = blockIdx.x * 256 + threadIdx.x;
  if (p < NE) ipos[perm[p]] = p;
}

// ---- rpos[p] = ipos[perm[p]^1]; psrc[p] = src[perm[p]] ----------------------
__global__ __launch_bounds__(256) void rpos_kernel(
    const int* __restrict__ perm, const int* __restrict__ ipos,
    const int* __restrict__ src, int* __restrict__ rpos, int* __restrict__ psrc)
{
  int p = blockIdx.x * 256 + threadIdx.x;
  if (p < NE) {
    int e = perm[p];
    rpos[p] = ipos[e ^ 1];
    psrc[p] = src[e];
  }
}

// ------- H0p[p] = relu([V[psrc[p]] || E[perm[p]]] @ Wi + bi), bf16 -----------
// Two-pass N-split (tiles 0..6 / 7..12): acc 104 -> 56 regs, occupancy up.
__global__ __launch_bounds__(256, 3) void h0_kernel(
    const unsigned short* __restrict__ Vb,   // [NN][LDV] bf16
    const unsigned short* __restrict__ Et,   // [NE][32] bf16 tail (k 128..159)
    const int* __restrict__ psrc,
    const unsigned short* __restrict__ Bp,   // packed Wi frags (CI chunks)
    const float* __restrict__ bi,
    bf16* __restrict__ H0)
{
  __shared__ float Sb[DH];
  const int tid = threadIdx.x;
  const int e0 = blockIdx.x * MT;
  if (tid < DH) Sb[tid] = bi[tid];
  const int wv = tid >> 6, ln = tid & 15, q = (tid & 63) >> 4;
  const int lane = tid & 63;
  __syncthreads();
  const int r0 = wv * 32 + ln;
  const int s0 = psrc[e0 + r0], s1 = psrc[e0 + r0 + 16];
  const unsigned short* v0p = Vb + (size_t)s0 * LDV;
  const unsigned short* v1p = Vb + (size_t)s1 * LDV;
  const unsigned short* e0p = Et + (size_t)(e0 + r0) * 32;
  const unsigned short* e1p = Et + (size_t)(e0 + r0 + 16) * 32;
  const unsigned short* bp = Bp + (size_t)lane * 8;
#pragma unroll
  for (int pass = 0; pass < 2; ++pass) {
    const int T0 = pass * 7;
    const int NTP = pass ? 6 : 7;
    f32x4 acc[7][2];
#pragma unroll
    for (int t = 0; t < 7; ++t)
#pragma unroll
      for (int m = 0; m < 2; ++m) acc[t][m] = (f32x4){0.f, 0.f, 0.f, 0.f};
    short8 bfr[7];
#pragma unroll
    for (int c = 0; c < 4; ++c) {
      short8 a0 = *(const short8*)(v0p + c * 32 + q * 8);
      short8 a1 = *(const short8*)(v1p + c * 32 + q * 8);
#pragma unroll
      for (int t = 0; t < NTP; ++t)
        bfr[t] = *(const short8*)(bp + (size_t)(c * NT + T0 + t) * 512);
#pragma unroll
      for (int t = 0; t < NTP; ++t) {
        acc[t][0] = MFMA(a0, bfr[t], acc[t][0]);
        acc[t][1] = MFMA(a1, bfr[t], acc[t][1]);
      }
    }
    {  // chunk 4: per-position tail
      short8 a0 = *(const short8*)(e0p + q * 8);
      short8 a1 = *(const short8*)(e1p + q * 8);
#pragma unroll
      for (int t = 0; t < NTP; ++t)
        bfr[t] = *(const short8*)(bp + (size_t)(4 * NT + T0 + t) * 512);
#pragma unroll
      for (int t = 0; t < NTP; ++t) {
        acc[t][0] = MFMA(a0, bfr[t], acc[t][0]);
        acc[t][1] = MFMA(a1, bfr[t], acc[t][1]);
      }
    }
#pragma unroll
    for (int t = 0; t < NTP; ++t) {
      int c = (T0 + t) * 16 + ln;
      if (c < DH) {
#pragma unroll
        for (int m = 0; m < 2; ++m)
#pragma unroll
          for (int i = 0; i < 4; ++i) {
            int e = e0 + wv * 32 + m * 16 + q * 4 + i;
            float h = acc[t][m][i] + Sb[c];
            H0[(size_t)e * DH + c] = __float2bfloat16(h > 0.f ? h : 0.f);
          }
      }
    }
    asm volatile("" ::: "memory");        // no cross-pass CSE/hoist
    __builtin_amdgcn_sched_barrier(0);
  }
}

// ---------------- Q = H @ Wh  (direct-reg, two-pass N-split) ------------------
__global__ __launch_bounds__(256, 4) void gemmq_kernel(
    const bf16* __restrict__ H,
    const unsigned short* __restrict__ Bp,   // packed Wh frags (CH chunks)
    bf16* __restrict__ Q)
{
  const int tid = threadIdx.x;
  const int e0 = blockIdx.x * MT;
  const int wv = tid >> 6, ln = tid & 15, q = (tid & 63) >> 4;
  const int lane = tid & 63;
  const unsigned short* Hs = (const unsigned short*)H;
  const unsigned short* a0p = Hs + (size_t)(e0 + wv * 32 + ln) * DH;
  const unsigned short* a1p = a0p + (size_t)16 * DH;
  const unsigned short* bp = Bp + (size_t)lane * 8;
#pragma unroll
  for (int pass = 0; pass < 2; ++pass) {
    const int T0 = pass * 7;
    const int NTP = pass ? 6 : 7;
    f32x4 acc[7][2];
#pragma unroll
    for (int t = 0; t < 7; ++t)
#pragma unroll
      for (int m = 0; m < 2; ++m) acc[t][m] = (f32x4){0.f, 0.f, 0.f, 0.f};
    short8 bfr[7];
#pragma unroll
    for (int c = 0; c < CH; ++c) {
      // last chunk reads past row end (cols 200..223): B is zero there (A*0=0)
      short8 a0 = *(const short8*)(a0p + c * 32 + q * 8);
      short8 a1 = *(const short8*)(a1p + c * 32 + q * 8);
#pragma unroll
      for (int t = 0; t < NTP; ++t)
        bfr[t] = *(const short8*)(bp + (size_t)(c * NT + T0 + t) * 512);
#pragma unroll
      for (int t = 0; t < NTP; ++t) {
        acc[t][0] = MFMA(a0, bfr[t], acc[t][0]);
        acc[t][1] = MFMA(a1, bfr[t], acc[t][1]);
      }
    }
#pragma unroll
    for (int t = 0; t < NTP; ++t) {
      int c = (T0 + t) * 16 + ln;
      if (c < DH) {
#pragma unroll
        for (int m = 0; m < 2; ++m)
#pragma unroll
          for (int i = 0; i < 4; ++i) {
            int e = e0 + wv * 32 + m * 16 + q * 4 + i;
            Q[(size_t)e * DH + c] = __float2bfloat16(acc[t][m][i]);
          }
      }
    }
    asm volatile("" ::: "memory");        // no cross-pass CSE/hoist
    __builtin_amdgcn_sched_barrier(0);
  }
}

// ------- fused per-node (perm-ordered storage):
// a = bh + sum_{p in seg(n)} Qp[p]   (SEQUENTIAL rows)
// for p in seg(n): rp = rpos[p];
//   val = relu(H0p[rp] + a - Qp[p]); write at (seqout? p : rp)
__global__ __launch_bounds__(256) void fusedmp_kernel(
    const bf16* __restrict__ Q, const bf16* __restrict__ H0,
    const int* __restrict__ offsets, const int* __restrict__ rpos,
    const float* __restrict__ bh, int seqout, bf16* __restrict__ Hout)
{
  int t = blockIdx.x * 256 + threadIdx.x;
  if (t >= NN * 25) return;
  int n = t / 25, g = t - n * 25;
  int st = offsets[n], en = offsets[n + 1];
  if (st == en) return;
  const unsigned short* Qs = (const unsigned short*)Q;
  const unsigned short* H0s = (const unsigned short*)H0;
  unsigned short* Os = (unsigned short*)Hout;
  float a[8];
  const float4* bp = (const float4*)(bh + g * 8);
  float4 b0 = bp[0], b1 = bp[1];
  a[0] = b0.x; a[1] = b0.y; a[2] = b0.z; a[3] = b0.w;
  a[4] = b1.x; a[5] = b1.y; a[6] = b1.z; a[7] = b1.w;
  for (int p = st; p < en; ++p) {               // sequential rows
    short8 u = *(const short8*)(Qs + (size_t)p * DH + g * 8);
#pragma unroll
    for (int k = 0; k < 8; ++k) a[k] += us2f((unsigned short)u[k]);
  }
  for (int p = st; p < en; ++p) {
    int rp = rpos[p];
    short8 uq = *(const short8*)(Qs + (size_t)p * DH + g * 8);    // L1 hit
    short8 uh = *(const short8*)(H0s + (size_t)rp * DH + g * 8);  // random row
    short8 w;
#pragma unroll
    for (int k = 0; k < 8; ++k) {
      float h = a[k] - us2f((unsigned short)uq[k]) + us2f((unsigned short)uh[k]);
      w[k] = (short)f2us(h > 0.f ? h : 0.f);
    }
    *(short8*)(Os + (size_t)(seqout ? p : rp) * DH + g * 8) = w;
  }
}

// --- Abuf[n][g*8..] = bf16( sum_{p in seg(n)} Hrev[p] )  -- fully sequential -
__global__ __launch_bounds__(256) void gatherseq_kernel(
    const bf16* __restrict__ Hrev, const int* __restrict__ offsets,
    unsigned short* __restrict__ Abuf)
{
  int t = blockIdx.x * 256 + threadIdx.x;
  if (t >= NN * 25) return;
  int n = t / 25, g = t - n * 25;
  int st = offsets[n], en = offsets[n + 1];
  float a[8];
#pragma unroll
  for (int k = 0; k < 8; ++k) a[k] = 0.f;
  const unsigned short* Hs = (const unsigned short*)Hrev;
  for (int p = st; p < en; ++p) {
    short8 u = *(const short8*)(Hs + (size_t)p * DH + g * 8);
#pragma unroll
    for (int k = 0; k < 8; ++k) a[k] += us2f((unsigned short)u[k]);
  }
  short8 w;
#pragma unroll
  for (int k = 0; k < 8; ++k) w[k] = (short)f2us(a[k]);
  *(short8*)&Abuf[(size_t)n * KO + g * 8] = w;
}

// ------- H_v = relu(A' @ Wo + bo), two-pass N-split, fp32 out ----------------
__global__ __launch_bounds__(256, 4) void out_kernel(
    const unsigned short* __restrict__ Abuf,  // [NNPAD][KO] bf16
    const unsigned short* __restrict__ Bp,    // packed Wo frags (CO chunks)
    const float* __restrict__ bo,
    float* __restrict__ out)
{
  __shared__ float Sb[DH];
  const int tid = threadIdx.x;
  const int n0 = blockIdx.x * MT;
  if (tid < DH) Sb[tid] = bo[tid];
  const int wv = tid >> 6, ln = tid & 15, q = (tid & 63) >> 4;
  const int lane = tid & 63;
  __syncthreads();
  const unsigned short* a0p = Abuf + (size_t)(n0 + wv * 32 + ln) * KO;
  const unsigned short* a1p = a0p + (size_t)16 * KO;
  const unsigned short* bp = Bp + (size_t)lane * 8;
#pragma unroll
  for (int pass = 0; pass < 2; ++pass) {
    const int T0 = pass * 7;
    const int NTP = pass ? 6 : 7;
    f32x4 acc[7][2];
#pragma unroll
    for (int t = 0; t < 7; ++t)
#pragma unroll
      for (int m = 0; m < 2; ++m) acc[t][m] = (f32x4){0.f, 0.f, 0.f, 0.f};
    short8 bfr[7];
#pragma unroll
    for (int c = 0; c < CO; ++c) {
      short8 a0 = *(const short8*)(a0p + c * 32 + q * 8);
      short8 a1 = *(const short8*)(a1p + c * 32 + q * 8);
#pragma unroll
      for (int t = 0; t < NTP; ++t)
        bfr[t] = *(const short8*)(bp + (size_t)(c * NT + T0 + t) * 512);
#pragma unroll
      for (int t = 0; t < NTP; ++t) {
        acc[t][0] = MFMA(a0, bfr[t], acc[t][0]);
        acc[t][1] = MFMA(a1, bfr[t], acc[t][1]);
      }
    }
#pragma unroll
    for (int t = 0; t < NTP; ++t) {
      int c = (T0 + t) * 16 + ln;
      if (c < DH) {
#pragma unroll
        for (int m = 0; m < 2; ++m)
#pragma unroll
          for (int i = 0; i < 4; ++i) {
            int n = n0 + wv * 32 + m * 16 + q * 4 + i;
            if (n < NN) {
              float h = acc[t][m][i] + Sb[c];
              out[(size_t)n * DH + c] = h > 0.f ? h : 0.f;
            }
          }
      }
    }
    asm volatile("" ::: "memory");        // no cross-pass CSE/hoist
    __builtin_amdgcn_sched_barrier(0);
  }
}

extern "C" void kernel_launch(void* const* d_in, const int* in_sizes, int n_in,
                              void* d_out, int out_size, void* d_ws, size_t ws_size,
                              hipStream_t stream)
{
  const float* V  = (const float*)d_in[0];
  const float* Ef = (const float*)d_in[1];
  const int* eidx = (const int*)d_in[2];   // [2, NE] -> row0 src, row1 dst
  const int* rev  = (const int*)d_in[3];   (void)rev;  // == e^1 (paired layout)
  const float* Wi = (const float*)d_in[4];
  const float* bi = (const float*)d_in[5];
  const float* Wh = (const float*)d_in[6];
  const float* bh = (const float*)d_in[7];
  const float* Wo = (const float*)d_in[8];
  const float* bo = (const float*)d_in[9];
  const int* src = eidx;
  const int* dst = eidx + NE;

  // ws: H0p 160MB | Hbp 160MB (Vb16 aliases head; Hrev reuses after gemmq2)
  //     | Q 160MB (Et / Abuf alias) | CSR + rpos/psrc + packed weights
  bf16* H0 = (bf16*)d_ws;
  bf16* Hb = H0 + (size_t)NE * DH;
  bf16* Q  = Hb + (size_t)NE * DH;
  unsigned short* Vb16 = (unsigned short*)Hb;  // dead before fusedmp1 writes Hb
  bf16* Hrev = Hb;                             // iter2 out (Hb dead after gemmq2)
  unsigned short* Et   = (unsigned short*)Q;   // dead after h0
  unsigned short* Abuf = (unsigned short*)Q;   // alive after fusedmp2
  int* counts   = (int*)(Q + (size_t)NE * DH);
  int* chunkSum = counts + NN;
  int* chunkOff = chunkSum + 1024;
  int* offsets  = chunkOff + 1024;
  int* cursor   = offsets + NN + 1;
  int* perm     = cursor + NN;
  int* ipos     = perm + NE;
  int* rpos     = ipos + NE;
  int* psrc     = rpos + NE;
  unsigned short* Bpi = (unsigned short*)(((uintptr_t)(psrc + NE) + 15) & ~(uintptr_t)15);
  unsigned short* Bph = Bpi + (size_t)CI * 832 * 8;
  unsigned short* Bpo = Bph + (size_t)CH * 832 * 8;

  const int gGE = NE / MT;                 // 3125
  const int gON = (NN + MT - 1) / MT;      // 1563
  const int gE  = (NE + 255) / 256;        // 1563
  const int gN  = (NN + 255) / 256;        // 782
  const int gG  = (NN * 25 + 255) / 256;   // 19532

  // ---- CSR build (by dst; out-edges of n are in-edges ^1) ----
  hipMemsetAsync(counts, 0, (size_t)NN * sizeof(int), stream);
  hist_kernel<<<gE, 256, 0, stream>>>(dst, counts);
  chunksum_kernel<<<NCH, 256, 0, stream>>>(counts, chunkSum);
  scanchunks_kernel<<<1, 1024, 0, stream>>>(chunkSum, chunkOff);
  scanlocal_kernel<<<gN, 256, 0, stream>>>(counts, chunkOff, offsets, cursor);
  scatter_kernel<<<gE, 256, 0, stream>>>(dst, cursor, perm);
  invperm_kernel<<<gE, 256, 0, stream>>>(perm, ipos);
  rpos_kernel<<<gE, 256, 0, stream>>>(perm, ipos, src, rpos, psrc);

  // ---- packed weights (MFMA fragment order, bf16, zero-padded) ----
  prepwpack_kernel<<<(CI * 832 + 255) / 256, 256, 0, stream>>>(Wi, DV + DE, CI, 0, Bpi);
  prepwpack_kernel<<<(CH * 832 + 255) / 256, 256, 0, stream>>>(Wh, DH, CH, 0, Bph);
  prepwpack_kernel<<<(CO * 832 + 255) / 256, 256, 0, stream>>>(Wo, 0, CO, 1, Bpo);

  // ---- V -> bf16 (into Vb16, aliases Hb; dead before fusedmp1 writes Hb) ----
  packv_kernel<<<(NN * (LDV / 8) + 255) / 256, 256, 0, stream>>>(V, Vb16);
  // ---- per-position tail (aliases Q; dead before gemmq1 writes Q) ----
  packet_kernel<<<(NE * 4 + 255) / 256, 256, 0, stream>>>(V, Ef, perm, psrc, Et);

  // ---- H0p (perm-ordered) ----
  h0_kernel<<<gGE, 256, 0, stream>>>(Vb16, Et, psrc, Bpi, bi, H0);

  // iter 1: Q = H0p@Wh; Hbp[rp] = relu(H0p[rp] + a_n - Qp[p])
  gemmq_kernel<<<gGE, 256, 0, stream>>>(H0, Bph, Q);
  fusedmp_kernel<<<gG, 256, 0, stream>>>(Q, H0, offsets, rpos, bh, 0, Hb);

  // iter 2: Q = Hbp@Wh; Hrev[p] = relu(H0p[rp] + a_n - Qp[p])  (seq write)
  gemmq_kernel<<<gGE, 256, 0, stream>>>(Hb, Bph, Q);
  fusedmp_kernel<<<gG, 256, 0, stream>>>(Q, H0, offsets, rpos, bh, 1, Hrev);

  // Q dead now: fill Abuf(=Q) V-columns + padding
  packav_kernel<<<(NNPAD * (KO / 8) + 255) / 256, 256, 0, stream>>>(V, Abuf);

  // readout: Mv[n] = sum_{p in seg(n)} Hrev[p]  (fully sequential)
  gatherseq_kernel<<<gG, 256, 0, stream>>>(Hrev, offsets, Abuf);
  out_kernel<<<gON, 256, 0, stream>>>(Abuf, Bpo, bo, (float*)d_out);
}

// Round 8
// 1294.601 us; speedup vs baseline: 1.0454x; 1.0454x over previous
//
#include <hip/hip_runtime.h>
#include <hip/hip_bf16.h>
#include <stdint.h>

typedef __hip_bfloat16 bf16;
typedef __attribute__((ext_vector_type(8))) short short8;
typedef __attribute__((ext_vector_type(4))) float f32x4;

#define NN 200000    // nodes
#define NNPAD 200064 // 3126*64
#define NE 400000    // directed edges
#define DV 133
#define DE 14
#define DH 200
#define MTW 64       // M rows per block (4 waves x 16 rows)
#define NT 13        // 13 col tiles of 16 (200 -> 208 padded)
#define NCH 782      // ceil(NN/256) scan chunks

#define CI 5         // K chunks Wi (147 -> 160)
#define CH 7         // K chunks Wh (200 -> 224)
#define CO 11        // K chunks Wo (333 -> 352)
#define KO 352
#define LDV 160      // Vb16 row stride (shorts)

#define MFMA(a, b, c) __builtin_amdgcn_mfma_f32_16x16x32_bf16((a), (b), (c), 0, 0, 0)

__device__ __forceinline__ float us2f(unsigned short u) {
  return __uint_as_float(((unsigned)u) << 16);
}
__device__ __forceinline__ unsigned short f2us(float f) {
  bf16 h = __float2bfloat16(f);
  return *reinterpret_cast<unsigned short*>(&h);
}

// ---- W pack into MFMA-fragment order --------------------------------------
__global__ __launch_bounds__(256) void prepwpack_kernel(
    const float* __restrict__ W, int Ksrc, int nchunks, int mode,
    unsigned short* __restrict__ out)
{
  int f = blockIdx.x * 256 + threadIdx.x;
  int total = nchunks * 13 * 64;
  if (f >= total) return;
  int c = f / 832, rem = f - c * 832;
  int t = rem >> 6, l = rem & 63;
  int q = l >> 4, ln = l & 15;
  int col = t * 16 + ln;
  short8 w;
#pragma unroll
  for (int j = 0; j < 8; ++j) {
    int k = c * 32 + q * 8 + j;
    float v = 0.f;
    if (col < DH) {
      if (mode == 0) {
        if (k < Ksrc) v = W[(size_t)k * DH + col];
      } else {
        if (k < 333) {
          int sr = (k < 200) ? (133 + k) : (k - 200);
          v = W[(size_t)sr * DH + col];
        }
      }
    }
    w[j] = (short)f2us(v);
  }
  *(short8*)&out[(size_t)f * 8] = w;
}

// -------- V -> bf16, padded row stride LDV (cols >= DV zero) -----------------
__global__ __launch_bounds__(256) void packv_kernel(
    const float* __restrict__ V, unsigned short* __restrict__ Vb)
{
  int idx = blockIdx.x * 256 + threadIdx.x;   // one short8 per thread
  if (idx >= NN * (LDV / 8)) return;
  int n = idx / (LDV / 8), g = idx - n * (LDV / 8);
  int k0 = g * 8;
  short8 w;
#pragma unroll
  for (int j = 0; j < 8; ++j) {
    int k = k0 + j;
    float v = (k < DV) ? V[(size_t)n * DV + k] : 0.f;
    w[j] = (short)f2us(v);
  }
  *(short8*)&Vb[(size_t)n * LDV + k0] = w;
}

// ---- per-position tail for h0 chunk 4: Et[p][0..31] = k 128..159 of
// [V[src[perm[p]]] || Ef[perm[p]]]
__global__ __launch_bounds__(256) void packet_kernel(
    const float* __restrict__ V, const float* __restrict__ Ef,
    const int* __restrict__ perm, const int* __restrict__ psrc,
    unsigned short* __restrict__ Et)
{
  int idx = blockIdx.x * 256 + threadIdx.x;
  if (idx >= NE * 4) return;
  int p = idx >> 2, part = idx & 3;
  int e = perm[p];
  short8 w;
#pragma unroll
  for (int j = 0; j < 8; ++j) w[j] = 0;
  if (part == 0) {
    int s = psrc[p];
#pragma unroll
    for (int j = 0; j < 5; ++j) w[j] = (short)f2us(V[(size_t)s * DV + 128 + j]);
#pragma unroll
    for (int j = 5; j < 8; ++j) w[j] = (short)f2us(Ef[(size_t)e * DE + (j - 5)]);
  } else if (part == 1) {
#pragma unroll
    for (int j = 0; j < 8; ++j) w[j] = (short)f2us(Ef[(size_t)e * DE + 3 + j]);
  } else if (part == 2) {
#pragma unroll
    for (int j = 0; j < 3; ++j) w[j] = (short)f2us(Ef[(size_t)e * DE + 11 + j]);
  }
  *(short8*)&Et[(size_t)p * 32 + part * 8] = w;
}

// ---- fill Abuf cols 200..351 with bf16(V), zero pad; zero rows >= NN --------
__global__ __launch_bounds__(256) void packav_kernel(
    const float* __restrict__ V, unsigned short* __restrict__ Abuf)
{
  int idx = blockIdx.x * 256 + threadIdx.x;   // one short8 per thread
  if (idx >= NNPAD * (KO / 8)) return;
  int n = idx / (KO / 8), g = idx - n * (KO / 8);
  int k0 = g * 8;
  if (n < NN && k0 < 200) return;             // gather owns these
  short8 w;
#pragma unroll
  for (int j = 0; j < 8; ++j) {
    int k = k0 + j;
    float v = (n < NN && k >= 200 && k < 333) ? V[(size_t)n * DV + (k - 200)] : 0.f;
    w[j] = (short)f2us(v);
  }
  *(short8*)&Abuf[(size_t)n * KO + k0] = w;
}

// ---------------- CSR build: hist -> scan -> scatter --------------------------
__global__ __launch_bounds__(256) void hist_kernel(
    const int* __restrict__ dst, int* __restrict__ counts)
{
  int e = blockIdx.x * 256 + threadIdx.x;
  if (e < NE) atomicAdd(&counts[dst[e]], 1);
}

__global__ __launch_bounds__(256) void chunksum_kernel(
    const int* __restrict__ counts, int* __restrict__ chunkSum)
{
  int b = blockIdx.x, tid = threadIdx.x;
  int i = b * 256 + tid;
  int v = (i < NN) ? counts[i] : 0;
#pragma unroll
  for (int d = 32; d; d >>= 1) v += __shfl_down(v, d, 64);
  __shared__ int ws[4];
  if ((tid & 63) == 0) ws[tid >> 6] = v;
  __syncthreads();
  if (tid == 0) chunkSum[b] = ws[0] + ws[1] + ws[2] + ws[3];
}

__global__ __launch_bounds__(1024) void scanchunks_kernel(
    const int* __restrict__ chunkSum, int* __restrict__ chunkOff)
{
  __shared__ int s[1024];
  int tid = threadIdx.x;
  int v = (tid < NCH) ? chunkSum[tid] : 0;
  s[tid] = v;
  __syncthreads();
  for (int d = 1; d < 1024; d <<= 1) {
    int t = (tid >= d) ? s[tid - d] : 0;
    __syncthreads();
    s[tid] += t;
    __syncthreads();
  }
  if (tid < NCH) chunkOff[tid] = s[tid] - v;  // exclusive
}

__global__ __launch_bounds__(256) void scanlocal_kernel(
    const int* __restrict__ counts, const int* __restrict__ chunkOff,
    int* __restrict__ offsets, int* __restrict__ cursor)
{
  __shared__ int s[256];
  int b = blockIdx.x, tid = threadIdx.x;
  int i = b * 256 + tid;
  int v = (i < NN) ? counts[i] : 0;
  s[tid] = v;
  __syncthreads();
  for (int d = 1; d < 256; d <<= 1) {
    int t = (tid >= d) ? s[tid - d] : 0;
    __syncthreads();
    s[tid] += t;
    __syncthreads();
  }
  if (i < NN) {
    int off = chunkOff[b] + s[tid] - v;
    offsets[i] = off;
    cursor[i] = off;
  }
  if (i == 0) offsets[NN] = NE;
}

__global__ __launch_bounds__(256) void scatter_kernel(
    const int* __restrict__ dst, int* __restrict__ cursor, int* __restrict__ perm)
{
  int e = blockIdx.x * 256 + threadIdx.x;
  if (e < NE) {
    int p = atomicAdd(&cursor[dst[e]], 1);
    perm[p] = e;
  }
}

// ---- ipos[perm[p]] = p ------------------------------------------------------
__global__ __launch_bounds__(256) void invperm_kernel(
    const int* __restrict__ perm, int* __restrict__ ipos)
{
  int p = blockIdx.x * 256 + threadIdx.x;
  if (p < NE) ipos[perm[p]] = p;
}

// ---- rpos[p] = ipos[perm[p]^1]; psrc[p] = src[perm[p]] ----------------------
__global__ __launch_bounds__(256) void rpos_kernel(
    const int* __restrict__ perm, const int* __restrict__ ipos,
    const int* __restrict__ src, int* __restrict__ rpos, int* __restrict__ psrc)
{
  int p = blockIdx.x * 256 + threadIdx.x;
  if (p < NE) {
    int e = perm[p];
    rpos[p] = ipos[e ^ 1];
    psrc[p] = src[e];
  }
}

// ------- H0p[p] = relu([V[psrc[p]] || E[perm[p]]] @ Wi + bi), bf16 -----------
// One 16-row tile per wave (acc 52 regs), 64 rows per block.
__global__ __launch_bounds__(256, 4) void h0_kernel(
    const unsigned short* __restrict__ Vb,   // [NN][LDV] bf16
    const unsigned short* __restrict__ Et,   // [NE][32] bf16 tail (k 128..159)
    const int* __restrict__ psrc,
    const unsigned short* __restrict__ Bp,   // packed Wi frags (CI chunks)
    const float* __restrict__ bi,
    bf16* __restrict__ H0)
{
  __shared__ float Sb[DH];
  const int tid = threadIdx.x;
  const int e0 = blockIdx.x * MTW;
  if (tid < DH) Sb[tid] = bi[tid];
  const int wv = tid >> 6, ln = tid & 15, q = (tid & 63) >> 4;
  const int lane = tid & 63;
  __syncthreads();
  f32x4 acc[NT];
#pragma unroll
  for (int t = 0; t < NT; ++t) acc[t] = (f32x4){0.f, 0.f, 0.f, 0.f};
  const int r0 = e0 + wv * 16 + ln;
  const int s0 = psrc[r0];
  const unsigned short* v0p = Vb + (size_t)s0 * LDV;
  const unsigned short* bp = Bp + (size_t)lane * 8;
  short8 bfr[NT];
#pragma unroll
  for (int c = 0; c < 4; ++c) {
    short8 a0 = *(const short8*)(v0p + c * 32 + q * 8);
#pragma unroll
    for (int t = 0; t < NT; ++t)
      bfr[t] = *(const short8*)(bp + (size_t)(c * NT + t) * 512);
#pragma unroll
    for (int t = 0; t < NT; ++t) acc[t] = MFMA(a0, bfr[t], acc[t]);
  }
  {  // chunk 4: per-position tail
    short8 a0 = *(const short8*)(Et + (size_t)r0 * 32 + q * 8);
#pragma unroll
    for (int t = 0; t < NT; ++t)
      bfr[t] = *(const short8*)(bp + (size_t)(4 * NT + t) * 512);
#pragma unroll
    for (int t = 0; t < NT; ++t) acc[t] = MFMA(a0, bfr[t], acc[t]);
  }
#pragma unroll
  for (int t = 0; t < NT; ++t) {
    int c = t * 16 + ln;
    if (c < DH) {
#pragma unroll
      for (int i = 0; i < 4; ++i) {
        int e = e0 + wv * 16 + q * 4 + i;
        float h = acc[t][i] + Sb[c];
        H0[(size_t)e * DH + c] = __float2bfloat16(h > 0.f ? h : 0.f);
      }
    }
  }
}

// ---------------- Q = H @ Wh  (direct-reg, 16 rows/wave) ----------------------
__global__ __launch_bounds__(256, 4) void gemmq_kernel(
    const bf16* __restrict__ H,
    const unsigned short* __restrict__ Bp,   // packed Wh frags (CH chunks)
    bf16* __restrict__ Q)
{
  const int tid = threadIdx.x;
  const int e0 = blockIdx.x * MTW;
  const int wv = tid >> 6, ln = tid & 15, q = (tid & 63) >> 4;
  const int lane = tid & 63;
  f32x4 acc[NT];
#pragma unroll
  for (int t = 0; t < NT; ++t) acc[t] = (f32x4){0.f, 0.f, 0.f, 0.f};
  const unsigned short* Hs = (const unsigned short*)H;
  const unsigned short* a0p = Hs + (size_t)(e0 + wv * 16 + ln) * DH;
  const unsigned short* bp = Bp + (size_t)lane * 8;
  short8 bfr[NT];
#pragma unroll
  for (int c = 0; c < CH; ++c) {
    // last chunk reads past row end (cols 200..223): B is zero there (A*0=0)
    short8 a0 = *(const short8*)(a0p + c * 32 + q * 8);
#pragma unroll
    for (int t = 0; t < NT; ++t)
      bfr[t] = *(const short8*)(bp + (size_t)(c * NT + t) * 512);
#pragma unroll
    for (int t = 0; t < NT; ++t) acc[t] = MFMA(a0, bfr[t], acc[t]);
  }
#pragma unroll
  for (int t = 0; t < NT; ++t) {
    int c = t * 16 + ln;
    if (c < DH) {
#pragma unroll
      for (int i = 0; i < 4; ++i) {
        int e = e0 + wv * 16 + q * 4 + i;
        Q[(size_t)e * DH + c] = __float2bfloat16(acc[t][i]);
      }
    }
  }
}

// ------- fused per-node (perm-ordered storage):
// a = bh + sum_{p in seg(n)} Qp[p]   (SEQUENTIAL rows)
// for p in seg(n): rp = rpos[p];
//   val = relu(H0p[rp] + a - Qp[p]); write at (seqout? p : rp)
__global__ __launch_bounds__(256) void fusedmp_kernel(
    const bf16* __restrict__ Q, const bf16* __restrict__ H0,
    const int* __restrict__ offsets, const int* __restrict__ rpos,
    const float* __restrict__ bh, int seqout, bf16* __restrict__ Hout)
{
  int t = blockIdx.x * 256 + threadIdx.x;
  if (t >= NN * 25) return;
  int n = t / 25, g = t - n * 25;
  int st = offsets[n], en = offsets[n + 1];
  if (st == en) return;
  const unsigned short* Qs = (const unsigned short*)Q;
  const unsigned short* H0s = (const unsigned short*)H0;
  unsigned short* Os = (unsigned short*)Hout;
  float a[8];
  const float4* bp = (const float4*)(bh + g * 8);
  float4 b0 = bp[0], b1 = bp[1];
  a[0] = b0.x; a[1] = b0.y; a[2] = b0.z; a[3] = b0.w;
  a[4] = b1.x; a[5] = b1.y; a[6] = b1.z; a[7] = b1.w;
  for (int p = st; p < en; ++p) {               // sequential rows
    short8 u = *(const short8*)(Qs + (size_t)p * DH + g * 8);
#pragma unroll
    for (int k = 0; k < 8; ++k) a[k] += us2f((unsigned short)u[k]);
  }
  for (int p = st; p < en; ++p) {
    int rp = rpos[p];
    short8 uq = *(const short8*)(Qs + (size_t)p * DH + g * 8);    // L1 hit
    short8 uh = *(const short8*)(H0s + (size_t)rp * DH + g * 8);  // random row
    short8 w;
#pragma unroll
    for (int k = 0; k < 8; ++k) {
      float h = a[k] - us2f((unsigned short)uq[k]) + us2f((unsigned short)uh[k]);
      w[k] = (short)f2us(h > 0.f ? h : 0.f);
    }
    *(short8*)(Os + (size_t)(seqout ? p : rp) * DH + g * 8) = w;
  }
}

// --- Abuf[n][g*8..] = bf16( sum_{p in seg(n)} Hrev[p] )  -- fully sequential -
__global__ __launch_bounds__(256) void gatherseq_kernel(
    const bf16* __restrict__ Hrev, const int* __restrict__ offsets,
    unsigned short* __restrict__ Abuf)
{
  int t = blockIdx.x * 256 + threadIdx.x;
  if (t >= NN * 25) return;
  int n = t / 25, g = t - n * 25;
  int st = offsets[n], en = offsets[n + 1];
  float a[8];
#pragma unroll
  for (int k = 0; k < 8; ++k) a[k] = 0.f;
  const unsigned short* Hs = (const unsigned short*)Hrev;
  for (int p = st; p < en; ++p) {
    short8 u = *(const short8*)(Hs + (size_t)p * DH + g * 8);
#pragma unroll
    for (int k = 0; k < 8; ++k) a[k] += us2f((unsigned short)u[k]);
  }
  short8 w;
#pragma unroll
  for (int k = 0; k < 8; ++k) w[k] = (short)f2us(a[k]);
  *(short8*)&Abuf[(size_t)n * KO + g * 8] = w;
}

// ------- H_v = relu(A' @ Wo + bo), 16 rows/wave, fp32 out --------------------
__global__ __launch_bounds__(256, 4) void out_kernel(
    const unsigned short* __restrict__ Abuf,  // [NNPAD][KO] bf16
    const unsigned short* __restrict__ Bp,    // packed Wo frags (CO chunks)
    const float* __restrict__ bo,
    float* __restrict__ out)
{
  __shared__ float Sb[DH];
  const int tid = threadIdx.x;
  const int n0 = blockIdx.x * MTW;
  if (tid < DH) Sb[tid] = bo[tid];
  const int wv = tid >> 6, ln = tid & 15, q = (tid & 63) >> 4;
  const int lane = tid & 63;
  __syncthreads();
  f32x4 acc[NT];
#pragma unroll
  for (int t = 0; t < NT; ++t) acc[t] = (f32x4){0.f, 0.f, 0.f, 0.f};
  const unsigned short* a0p = Abuf + (size_t)(n0 + wv * 16 + ln) * KO;
  const unsigned short* bp = Bp + (size_t)lane * 8;
  short8 bfr[NT];
#pragma unroll
  for (int c = 0; c < CO; ++c) {
    short8 a0 = *(const short8*)(a0p + c * 32 + q * 8);
#pragma unroll
    for (int t = 0; t < NT; ++t)
      bfr[t] = *(const short8*)(bp + (size_t)(c * NT + t) * 512);
#pragma unroll
    for (int t = 0; t < NT; ++t) acc[t] = MFMA(a0, bfr[t], acc[t]);
  }
#pragma unroll
  for (int t = 0; t < NT; ++t) {
    int c = t * 16 + ln;
    if (c < DH) {
#pragma unroll
      for (int i = 0; i < 4; ++i) {
        int n = n0 + wv * 16 + q * 4 + i;
        if (n < NN) {
          float h = acc[t][i] + Sb[c];
          out[(size_t)n * DH + c] = h > 0.f ? h : 0.f;
        }
      }
    }
  }
}

extern "C" void kernel_launch(void* const* d_in, const int* in_sizes, int n_in,
                              void* d_out, int out_size, void* d_ws, size_t ws_size,
                              hipStream_t stream)
{
  const float* V  = (const float*)d_in[0];
  const float* Ef = (const float*)d_in[1];
  const int* eidx = (const int*)d_in[2];   // [2, NE] -> row0 src, row1 dst
  const int* rev  = (const int*)d_in[3];   (void)rev;  // == e^1 (paired layout)
  const float* Wi = (const float*)d_in[4];
  const float* bi = (const float*)d_in[5];
  const float* Wh = (const float*)d_in[6];
  const float* bh = (const float*)d_in[7];
  const float* Wo = (const float*)d_in[8];
  const float* bo = (const float*)d_in[9];
  const int* src = eidx;
  const int* dst = eidx + NE;

  // ws: H0p 160MB | Hbp 160MB (Vb16 aliases head; Hrev reuses after gemmq2)
  //     | Q 160MB (Et / Abuf alias) | CSR + rpos/psrc + packed weights
  bf16* H0 = (bf16*)d_ws;
  bf16* Hb = H0 + (size_t)NE * DH;
  bf16* Q  = Hb + (size_t)NE * DH;
  unsigned short* Vb16 = (unsigned short*)Hb;  // dead before fusedmp1 writes Hb
  bf16* Hrev = Hb;                             // iter2 out (Hb dead after gemmq2)
  unsigned short* Et   = (unsigned short*)Q;   // dead after h0
  unsigned short* Abuf = (unsigned short*)Q;   // alive after fusedmp2
  int* counts   = (int*)(Q + (size_t)NE * DH);
  int* chunkSum = counts + NN;
  int* chunkOff = chunkSum + 1024;
  int* offsets  = chunkOff + 1024;
  int* cursor   = offsets + NN + 1;
  int* perm     = cursor + NN;
  int* ipos     = perm + NE;
  int* rpos     = ipos + NE;
  int* psrc     = rpos + NE;
  unsigned short* Bpi = (unsigned short*)(((uintptr_t)(psrc + NE) + 15) & ~(uintptr_t)15);
  unsigned short* Bph = Bpi + (size_t)CI * 832 * 8;
  unsigned short* Bpo = Bph + (size_t)CH * 832 * 8;

  const int gGE = NE / MTW;                // 6250
  const int gON = NNPAD / MTW;             // 3126
  const int gE  = (NE + 255) / 256;        // 1563
  const int gN  = (NN + 255) / 256;        // 782
  const int gG  = (NN * 25 + 255) / 256;   // 19532

  // ---- CSR build (by dst; out-edges of n are in-edges ^1) ----
  hipMemsetAsync(counts, 0, (size_t)NN * sizeof(int), stream);
  hist_kernel<<<gE, 256, 0, stream>>>(dst, counts);
  chunksum_kernel<<<NCH, 256, 0, stream>>>(counts, chunkSum);
  scanchunks_kernel<<<1, 1024, 0, stream>>>(chunkSum, chunkOff);
  scanlocal_kernel<<<gN, 256, 0, stream>>>(counts, chunkOff, offsets, cursor);
  scatter_kernel<<<gE, 256, 0, stream>>>(dst, cursor, perm);
  invperm_kernel<<<gE, 256, 0, stream>>>(perm, ipos);
  rpos_kernel<<<gE, 256, 0, stream>>>(perm, ipos, src, rpos, psrc);

  // ---- packed weights (MFMA fragment order, bf16, zero-padded) ----
  prepwpack_kernel<<<(CI * 832 + 255) / 256, 256, 0, stream>>>(Wi, DV + DE, CI, 0, Bpi);
  prepwpack_kernel<<<(CH * 832 + 255) / 256, 256, 0, stream>>>(Wh, DH, CH, 0, Bph);
  prepwpack_kernel<<<(CO * 832 + 255) / 256, 256, 0, stream>>>(Wo, 0, CO, 1, Bpo);

  // ---- V -> bf16 (into Vb16, aliases Hb; dead before fusedmp1 writes Hb) ----
  packv_kernel<<<(NN * (LDV / 8) + 255) / 256, 256, 0, stream>>>(V, Vb16);
  // ---- per-position tail (aliases Q; dead before gemmq1 writes Q) ----
  packet_kernel<<<(NE * 4 + 255) / 256, 256, 0, stream>>>(V, Ef, perm, psrc, Et);

  // ---- H0p (perm-ordered) ----
  h0_kernel<<<gGE, 256, 0, stream>>>(Vb16, Et, psrc, Bpi, bi, H0);

  // iter 1: Q = H0p@Wh; Hbp[rp] = relu(H0p[rp] + a_n - Qp[p])
  gemmq_kernel<<<gGE, 256, 0, stream>>>(H0, Bph, Q);
  fusedmp_kernel<<<gG, 256, 0, stream>>>(Q, H0, offsets, rpos, bh, 0, Hb);

  // iter 2: Q = Hbp@Wh; Hrev[p] = relu(H0p[rp] + a_n - Qp[p])  (seq write)
  gemmq_kernel<<<gGE, 256, 0, stream>>>(Hb, Bph, Q);
  fusedmp_kernel<<<gG, 256, 0, stream>>>(Q, H0, offsets, rpos, bh, 1, Hrev);

  // Q dead now: fill Abuf(=Q) V-columns + padding
  packav_kernel<<<(NNPAD * (KO / 8) + 255) / 256, 256, 0, stream>>>(V, Abuf);

  // readout: Mv[n] = sum_{p in seg(n)} Hrev[p]  (fully sequential)
  gatherseq_kernel<<<gG, 256, 0, stream>>>(Hrev, offsets, Abuf);
  out_kernel<<<gON, 256, 0, stream>>>(Abuf, Bpo, bo, (float*)d_out);
}

// Round 9
// 1196.748 us; speedup vs baseline: 1.1309x; 1.0818x over previous
//
#include <hip/hip_runtime.h>
#include <hip/hip_bf16.h>
#include <stdint.h>

typedef __hip_bfloat16 bf16;
typedef __attribute__((ext_vector_type(8))) short short8;
typedef __attribute__((ext_vector_type(4))) float f32x4;

#define NN 200000    // nodes
#define NNPAD 200064 // 1563*128
#define NE 400000    // directed edges
#define DV 133
#define DE 14
#define DH 200
#define MT 128       // M rows per block
#define NT 13        // 13 col tiles of 16 (200 -> 208 padded)
#define NCH 782      // ceil(NN/256) scan chunks

#define CI 5         // K chunks Wi (147 -> 160)
#define CH 7         // K chunks Wh (200 -> 224)
#define CO 11        // K chunks Wo (333 -> 352)
#define KO 352
#define LDV 160      // Vb16 row stride (shorts)

#define MFMA(a, b, c) __builtin_amdgcn_mfma_f32_16x16x32_bf16((a), (b), (c), 0, 0, 0)

__device__ __forceinline__ float us2f(unsigned short u) {
  return __uint_as_float(((unsigned)u) << 16);
}
__device__ __forceinline__ unsigned short f2us(float f) {
  bf16 h = __float2bfloat16(f);
  return *reinterpret_cast<unsigned short*>(&h);
}

// ---- W pack into MFMA-fragment order --------------------------------------
__global__ __launch_bounds__(256) void prepwpack_kernel(
    const float* __restrict__ W, int Ksrc, int nchunks, int mode,
    unsigned short* __restrict__ out)
{
  int f = blockIdx.x * 256 + threadIdx.x;
  int total = nchunks * 13 * 64;
  if (f >= total) return;
  int c = f / 832, rem = f - c * 832;
  int t = rem >> 6, l = rem & 63;
  int q = l >> 4, ln = l & 15;
  int col = t * 16 + ln;
  short8 w;
#pragma unroll
  for (int j = 0; j < 8; ++j) {
    int k = c * 32 + q * 8 + j;
    float v = 0.f;
    if (col < DH) {
      if (mode == 0) {
        if (k < Ksrc) v = W[(size_t)k * DH + col];
      } else {
        if (k < 333) {
          int sr = (k < 200) ? (133 + k) : (k - 200);
          v = W[(size_t)sr * DH + col];
        }
      }
    }
    w[j] = (short)f2us(v);
  }
  *(short8*)&out[(size_t)f * 8] = w;
}

// -------- V -> bf16, padded row stride LDV (cols >= DV zero) -----------------
__global__ __launch_bounds__(256) void packv_kernel(
    const float* __restrict__ V, unsigned short* __restrict__ Vb)
{
  int idx = blockIdx.x * 256 + threadIdx.x;   // one short8 per thread
  if (idx >= NN * (LDV / 8)) return;
  int n = idx / (LDV / 8), g = idx - n * (LDV / 8);
  int k0 = g * 8;
  short8 w;
#pragma unroll
  for (int j = 0; j < 8; ++j) {
    int k = k0 + j;
    float v = (k < DV) ? V[(size_t)n * DV + k] : 0.f;
    w[j] = (short)f2us(v);
  }
  *(short8*)&Vb[(size_t)n * LDV + k0] = w;
}

// ---- per-position tail for h0 chunk 4: Et[p][0..31] = k 128..159 of
// [V[src[perm[p]]] || Ef[perm[p]]]
__global__ __launch_bounds__(256) void packet_kernel(
    const float* __restrict__ V, const float* __restrict__ Ef,
    const int* __restrict__ perm, const int* __restrict__ psrc,
    unsigned short* __restrict__ Et)
{
  int idx = blockIdx.x * 256 + threadIdx.x;
  if (idx >= NE * 4) return;
  int p = idx >> 2, part = idx & 3;
  int e = perm[p];
  short8 w;
#pragma unroll
  for (int j = 0; j < 8; ++j) w[j] = 0;
  if (part == 0) {
    int s = psrc[p];
#pragma unroll
    for (int j = 0; j < 5; ++j) w[j] = (short)f2us(V[(size_t)s * DV + 128 + j]);
#pragma unroll
    for (int j = 5; j < 8; ++j) w[j] = (short)f2us(Ef[(size_t)e * DE + (j - 5)]);
  } else if (part == 1) {
#pragma unroll
    for (int j = 0; j < 8; ++j) w[j] = (short)f2us(Ef[(size_t)e * DE + 3 + j]);
  } else if (part == 2) {
#pragma unroll
    for (int j = 0; j < 3; ++j) w[j] = (short)f2us(Ef[(size_t)e * DE + 11 + j]);
  }
  *(short8*)&Et[(size_t)p * 32 + part * 8] = w;
}

// ---- fill Abuf cols 200..351 with bf16(V), zero pad; zero rows >= NN --------
__global__ __launch_bounds__(256) void packav_kernel(
    const float* __restrict__ V, unsigned short* __restrict__ Abuf)
{
  int idx = blockIdx.x * 256 + threadIdx.x;   // one short8 per thread
  if (idx >= NNPAD * (KO / 8)) return;
  int n = idx / (KO / 8), g = idx - n * (KO / 8);
  int k0 = g * 8;
  if (n < NN && k0 < 200) return;             // gather owns these
  short8 w;
#pragma unroll
  for (int j = 0; j < 8; ++j) {
    int k = k0 + j;
    float v = (n < NN && k >= 200 && k < 333) ? V[(size_t)n * DV + (k - 200)] : 0.f;
    w[j] = (short)f2us(v);
  }
  *(short8*)&Abuf[(size_t)n * KO + k0] = w;
}

// ---------------- CSR build: hist -> scan -> scatter --------------------------
__global__ __launch_bounds__(256) void hist_kernel(
    const int* __restrict__ dst, int* __restrict__ counts)
{
  int e = blockIdx.x * 256 + threadIdx.x;
  if (e < NE) atomicAdd(&counts[dst[e]], 1);
}

__global__ __launch_bounds__(256) void chunksum_kernel(
    const int* __restrict__ counts, int* __restrict__ chunkSum)
{
  int b = blockIdx.x, tid = threadIdx.x;
  int i = b * 256 + tid;
  int v = (i < NN) ? counts[i] : 0;
#pragma unroll
  for (int d = 32; d; d >>= 1) v += __shfl_down(v, d, 64);
  __shared__ int ws[4];
  if ((tid & 63) == 0) ws[tid >> 6] = v;
  __syncthreads();
  if (tid == 0) chunkSum[b] = ws[0] + ws[1] + ws[2] + ws[3];
}

__global__ __launch_bounds__(1024) void scanchunks_kernel(
    const int* __restrict__ chunkSum, int* __restrict__ chunkOff)
{
  __shared__ int s[1024];
  int tid = threadIdx.x;
  int v = (tid < NCH) ? chunkSum[tid] : 0;
  s[tid] = v;
  __syncthreads();
  for (int d = 1; d < 1024; d <<= 1) {
    int t = (tid >= d) ? s[tid - d] : 0;
    __syncthreads();
    s[tid] += t;
    __syncthreads();
  }
  if (tid < NCH) chunkOff[tid] = s[tid] - v;  // exclusive
}

__global__ __launch_bounds__(256) void scanlocal_kernel(
    const int* __restrict__ counts, const int* __restrict__ chunkOff,
    int* __restrict__ offsets, int* __restrict__ cursor)
{
  __shared__ int s[256];
  int b = blockIdx.x, tid = threadIdx.x;
  int i = b * 256 + tid;
  int v = (i < NN) ? counts[i] : 0;
  s[tid] = v;
  __syncthreads();
  for (int d = 1; d < 256; d <<= 1) {
    int t = (tid >= d) ? s[tid - d] : 0;
    __syncthreads();
    s[tid] += t;
    __syncthreads();
  }
  if (i < NN) {
    int off = chunkOff[b] + s[tid] - v;
    offsets[i] = off;
    cursor[i] = off;
  }
  if (i == 0) offsets[NN] = NE;
}

__global__ __launch_bounds__(256) void scatter_kernel(
    const int* __restrict__ dst, int* __restrict__ cursor, int* __restrict__ perm)
{
  int e = blockIdx.x * 256 + threadIdx.x;
  if (e < NE) {
    int p = atomicAdd(&cursor[dst[e]], 1);
    perm[p] = e;
  }
}

// ---- ipos[perm[p]] = p ------------------------------------------------------
__global__ __launch_bounds__(256) void invperm_kernel(
    const int* __restrict__ perm, int* __restrict__ ipos)
{
  int p = blockIdx.x * 256 + threadIdx.x;
  if (p < NE) ipos[perm[p]] = p;
}

// ---- rpos[p] = ipos[perm[p]^1]; psrc[p] = src[perm[p]] ----------------------
__global__ __launch_bounds__(256) void rpos_kernel(
    const int* __restrict__ perm, const int* __restrict__ ipos,
    const int* __restrict__ src, int* __restrict__ rpos, int* __restrict__ psrc)
{
  int p = blockIdx.x * 256 + threadIdx.x;
  if (p < NE) {
    int e = perm[p];
    rpos[p] = ipos[e ^ 1];
    psrc[p] = src[e];
  }
}

// ------- H0p[p] = relu([V[psrc[p]] || E[perm[p]]] @ Wi + bi), bf16 -----------
// B chunks 0..3 staged in LDS once (52KB, 1 barrier); chunk 4 B from global.
__global__ __launch_bounds__(256) void h0_kernel(
    const unsigned short* __restrict__ Vb,   // [NN][LDV] bf16
    const unsigned short* __restrict__ Et,   // [NE][32] bf16 tail (k 128..159)
    const int* __restrict__ psrc,
    const unsigned short* __restrict__ Bp,   // packed Wi frags (CI chunks)
    const float* __restrict__ bi,
    bf16* __restrict__ H0)
{
  __shared__ __align__(16) unsigned short Bs[4 * 832 * 8];  // 52KB
  __shared__ float Sb[DH];
  const int tid = threadIdx.x;
  const int e0 = blockIdx.x * MT;
  if (tid < DH) Sb[tid] = bi[tid];
  const int wv = tid >> 6, ln = tid & 15, q = (tid & 63) >> 4;
  const int lane = tid & 63;
  f32x4 acc[NT][2];
#pragma unroll
  for (int t = 0; t < NT; ++t)
#pragma unroll
    for (int m = 0; m < 2; ++m) acc[t][m] = (f32x4){0.f, 0.f, 0.f, 0.f};
  const int r0 = e0 + wv * 32 + ln;
  const int s0 = psrc[r0], s1 = psrc[r0 + 16];
  const unsigned short* v0p = Vb + (size_t)s0 * LDV;
  const unsigned short* v1p = Vb + (size_t)s1 * LDV;
  // stage B chunks 0..3 (3328 x 16B)
  for (int i = tid; i < 3328; i += 256)
    *(short8*)&Bs[(size_t)i * 8] = *(const short8*)&Bp[(size_t)i * 8];
  __syncthreads();
#pragma unroll
  for (int c = 0; c < 4; ++c) {
    short8 a0 = *(const short8*)(v0p + c * 32 + q * 8);
    short8 a1 = *(const short8*)(v1p + c * 32 + q * 8);
    short8 bfr[NT];
#pragma unroll
    for (int t = 0; t < NT; ++t)
      bfr[t] = *(const short8*)&Bs[(size_t)((c * NT + t) * 64 + lane) * 8];
#pragma unroll
    for (int t = 0; t < NT; ++t) {
      acc[t][0] = MFMA(a0, bfr[t], acc[t][0]);
      acc[t][1] = MFMA(a1, bfr[t], acc[t][1]);
    }
  }
  {  // chunk 4: per-position tail; B direct from global (13KB, L2-hot)
    short8 a0 = *(const short8*)(Et + (size_t)r0 * 32 + q * 8);
    short8 a1 = *(const short8*)(Et + (size_t)(r0 + 16) * 32 + q * 8);
    short8 bfr[NT];
#pragma unroll
    for (int t = 0; t < NT; ++t)
      bfr[t] = *(const short8*)&Bp[(size_t)((4 * NT + t) * 64 + lane) * 8];
#pragma unroll
    for (int t = 0; t < NT; ++t) {
      acc[t][0] = MFMA(a0, bfr[t], acc[t][0]);
      acc[t][1] = MFMA(a1, bfr[t], acc[t][1]);
    }
  }
#pragma unroll
  for (int t = 0; t < NT; ++t) {
    int c = t * 16 + ln;
    if (c < DH) {
#pragma unroll
      for (int m = 0; m < 2; ++m)
#pragma unroll
        for (int i = 0; i < 4; ++i) {
          int e = e0 + wv * 32 + m * 16 + q * 4 + i;
          float h = acc[t][m][i] + Sb[c];
          H0[(size_t)e * DH + c] = __float2bfloat16(h > 0.f ? h : 0.f);
        }
    }
  }
}

// ---------------- Q = H @ Wh  (LDS-staged B, 2 phases, 3 barriers) -----------
__global__ __launch_bounds__(256) void gemmq_kernel(
    const bf16* __restrict__ H,
    const unsigned short* __restrict__ Bp,   // packed Wh frags (CH chunks)
    bf16* __restrict__ Q)
{
  __shared__ __align__(16) unsigned short Bs[4 * 832 * 8];  // 52KB
  const int tid = threadIdx.x;
  const int e0 = blockIdx.x * MT;
  const int wv = tid >> 6, ln = tid & 15, q = (tid & 63) >> 4;
  const int lane = tid & 63;
  f32x4 acc[NT][2];
#pragma unroll
  for (int t = 0; t < NT; ++t)
#pragma unroll
    for (int m = 0; m < 2; ++m) acc[t][m] = (f32x4){0.f, 0.f, 0.f, 0.f};
  const unsigned short* Hs = (const unsigned short*)H;
  const unsigned short* a0p = Hs + (size_t)(e0 + wv * 32 + ln) * DH;
  const unsigned short* a1p = a0p + (size_t)16 * DH;
  // prefetch phase-2 A rows (chunks 4..6) so the mid barrier hides their latency
  short8 a2[3][2];
#pragma unroll
  for (int c = 4; c < CH; ++c) {
    a2[c - 4][0] = *(const short8*)(a0p + c * 32 + q * 8);
    a2[c - 4][1] = *(const short8*)(a1p + c * 32 + q * 8);
  }
  // stage B chunks 0..3
  for (int i = tid; i < 3328; i += 256)
    *(short8*)&Bs[(size_t)i * 8] = *(const short8*)&Bp[(size_t)i * 8];
  __syncthreads();
#pragma unroll
  for (int c = 0; c < 4; ++c) {
    short8 a0 = *(const short8*)(a0p + c * 32 + q * 8);
    short8 a1 = *(const short8*)(a1p + c * 32 + q * 8);
    short8 bfr[NT];
#pragma unroll
    for (int t = 0; t < NT; ++t)
      bfr[t] = *(const short8*)&Bs[(size_t)((c * NT + t) * 64 + lane) * 8];
#pragma unroll
    for (int t = 0; t < NT; ++t) {
      acc[t][0] = MFMA(a0, bfr[t], acc[t][0]);
      acc[t][1] = MFMA(a1, bfr[t], acc[t][1]);
    }
  }
  __syncthreads();
  // stage B chunks 4..6
  for (int i = tid; i < 2496; i += 256)
    *(short8*)&Bs[(size_t)i * 8] = *(const short8*)&Bp[(size_t)(3328 + i) * 8];
  __syncthreads();
#pragma unroll
  for (int c = 4; c < CH; ++c) {
    short8 bfr[NT];
#pragma unroll
    for (int t = 0; t < NT; ++t)
      bfr[t] = *(const short8*)&Bs[(size_t)(((c - 4) * NT + t) * 64 + lane) * 8];
#pragma unroll
    for (int t = 0; t < NT; ++t) {
      acc[t][0] = MFMA(a2[c - 4][0], bfr[t], acc[t][0]);
      acc[t][1] = MFMA(a2[c - 4][1], bfr[t], acc[t][1]);
    }
  }
#pragma unroll
  for (int t = 0; t < NT; ++t) {
    int c = t * 16 + ln;
    if (c < DH) {
#pragma unroll
      for (int m = 0; m < 2; ++m)
#pragma unroll
        for (int i = 0; i < 4; ++i) {
          int e = e0 + wv * 32 + m * 16 + q * 4 + i;
          Q[(size_t)e * DH + c] = __float2bfloat16(acc[t][m][i]);
        }
    }
  }
}

// ------- fused per-node (perm-ordered storage):
// a = bh + sum_{p in seg(n)} Qp[p]   (SEQUENTIAL rows)
// for p in seg(n): rp = rpos[p];
//   val = relu(H0p[rp] + a - Qp[p]); write at (seqout? p : rp)
__global__ __launch_bounds__(256) void fusedmp_kernel(
    const bf16* __restrict__ Q, const bf16* __restrict__ H0,
    const int* __restrict__ offsets, const int* __restrict__ rpos,
    const float* __restrict__ bh, int seqout, bf16* __restrict__ Hout)
{
  int t = blockIdx.x * 256 + threadIdx.x;
  if (t >= NN * 25) return;
  int n = t / 25, g = t - n * 25;
  int st = offsets[n], en = offsets[n + 1];
  if (st == en) return;
  const unsigned short* Qs = (const unsigned short*)Q;
  const unsigned short* H0s = (const unsigned short*)H0;
  unsigned short* Os = (unsigned short*)Hout;
  float a[8];
  const float4* bp = (const float4*)(bh + g * 8);
  float4 b0 = bp[0], b1 = bp[1];
  a[0] = b0.x; a[1] = b0.y; a[2] = b0.z; a[3] = b0.w;
  a[4] = b1.x; a[5] = b1.y; a[6] = b1.z; a[7] = b1.w;
  for (int p = st; p < en; ++p) {               // sequential rows
    short8 u = *(const short8*)(Qs + (size_t)p * DH + g * 8);
#pragma unroll
    for (int k = 0; k < 8; ++k) a[k] += us2f((unsigned short)u[k]);
  }
  for (int p = st; p < en; ++p) {
    int rp = rpos[p];
    short8 uq = *(const short8*)(Qs + (size_t)p * DH + g * 8);    // L1 hit
    short8 uh = *(const short8*)(H0s + (size_t)rp * DH + g * 8);  // random row
    short8 w;
#pragma unroll
    for (int k = 0; k < 8; ++k) {
      float h = a[k] - us2f((unsigned short)uq[k]) + us2f((unsigned short)uh[k]);
      w[k] = (short)f2us(h > 0.f ? h : 0.f);
    }
    *(short8*)(Os + (size_t)(seqout ? p : rp) * DH + g * 8) = w;
  }
}

// --- Abuf[n][g*8..] = bf16( sum_{p in seg(n)} Hrev[p] )  -- fully sequential -
__global__ __launch_bounds__(256) void gatherseq_kernel(
    const bf16* __restrict__ Hrev, const int* __restrict__ offsets,
    unsigned short* __restrict__ Abuf)
{
  int t = blockIdx.x * 256 + threadIdx.x;
  if (t >= NN * 25) return;
  int n = t / 25, g = t - n * 25;
  int st = offsets[n], en = offsets[n + 1];
  float a[8];
#pragma unroll
  for (int k = 0; k < 8; ++k) a[k] = 0.f;
  const unsigned short* Hs = (const unsigned short*)Hrev;
  for (int p = st; p < en; ++p) {
    short8 u = *(const short8*)(Hs + (size_t)p * DH + g * 8);
#pragma unroll
    for (int k = 0; k < 8; ++k) a[k] += us2f((unsigned short)u[k]);
  }
  short8 w;
#pragma unroll
  for (int k = 0; k < 8; ++k) w[k] = (short)f2us(a[k]);
  *(short8*)&Abuf[(size_t)n * KO + g * 8] = w;
}

// ------- H_v = relu(A' @ Wo + bo), LDS-staged B (3 phases), fp32 out ---------
__global__ __launch_bounds__(256) void out_kernel(
    const unsigned short* __restrict__ Abuf,  // [NNPAD][KO] bf16
    const unsigned short* __restrict__ Bp,    // packed Wo frags (CO chunks)
    const float* __restrict__ bo,
    float* __restrict__ out)
{
  __shared__ __align__(16) unsigned short Bs[4 * 832 * 8];  // 52KB
  __shared__ float Sb[DH];
  const int tid = threadIdx.x;
  const int n0 = blockIdx.x * MT;
  if (tid < DH) Sb[tid] = bo[tid];
  const int wv = tid >> 6, ln = tid & 15, q = (tid & 63) >> 4;
  const int lane = tid & 63;
  f32x4 acc[NT][2];
#pragma unroll
  for (int t = 0; t < NT; ++t)
#pragma unroll
    for (int m = 0; m < 2; ++m) acc[t][m] = (f32x4){0.f, 0.f, 0.f, 0.f};
  const unsigned short* a0p = Abuf + (size_t)(n0 + wv * 32 + ln) * KO;
  const unsigned short* a1p = a0p + (size_t)16 * KO;
  // 3 phases: chunks [0,4), [4,8), [8,11)
#pragma unroll
  for (int ph = 0; ph < 3; ++ph) {
    const int c0 = ph * 4;
    const int nc = (ph == 2) ? 3 : 4;
    const int units = nc * 832;
    if (ph) __syncthreads();                    // drain readers of prev phase
    for (int i = tid; i < units; i += 256)
      *(short8*)&Bs[(size_t)i * 8] = *(const short8*)&Bp[(size_t)(c0 * 832 + i) * 8];
    __syncthreads();
    for (int cc = 0; cc < nc; ++cc) {
      int c = c0 + cc;
      short8 a0 = *(const short8*)(a0p + c * 32 + q * 8);
      short8 a1 = *(const short8*)(a1p + c * 32 + q * 8);
      short8 bfr[NT];
#pragma unroll
      for (int t = 0; t < NT; ++t)
        bfr[t] = *(const short8*)&Bs[(size_t)((cc * NT + t) * 64 + lane) * 8];
#pragma unroll
      for (int t = 0; t < NT; ++t) {
        acc[t][0] = MFMA(a0, bfr[t], acc[t][0]);
        acc[t][1] = MFMA(a1, bfr[t], acc[t][1]);
      }
    }
  }
#pragma unroll
  for (int t = 0; t < NT; ++t) {
    int c = t * 16 + ln;
    if (c < DH) {
#pragma unroll
      for (int m = 0; m < 2; ++m)
#pragma unroll
        for (int i = 0; i < 4; ++i) {
          int n = n0 + wv * 32 + m * 16 + q * 4 + i;
          if (n < NN) {
            float h = acc[t][m][i] + Sb[c];
            out[(size_t)n * DH + c] = h > 0.f ? h : 0.f;
          }
        }
    }
  }
}

extern "C" void kernel_launch(void* const* d_in, const int* in_sizes, int n_in,
                              void* d_out, int out_size, void* d_ws, size_t ws_size,
                              hipStream_t stream)
{
  const float* V  = (const float*)d_in[0];
  const float* Ef = (const float*)d_in[1];
  const int* eidx = (const int*)d_in[2];   // [2, NE] -> row0 src, row1 dst
  const int* rev  = (const int*)d_in[3];   (void)rev;  // == e^1 (paired layout)
  const float* Wi = (const float*)d_in[4];
  const float* bi = (const float*)d_in[5];
  const float* Wh = (const float*)d_in[6];
  const float* bh = (const float*)d_in[7];
  const float* Wo = (const float*)d_in[8];
  const float* bo = (const float*)d_in[9];
  const int* src = eidx;
  const int* dst = eidx + NE;

  // ws: H0p 160MB | Hbp 160MB (Vb16 aliases head; Hrev reuses after gemmq2)
  //     | Q 160MB (Et / Abuf alias) | CSR + rpos/psrc + packed weights
  bf16* H0 = (bf16*)d_ws;
  bf16* Hb = H0 + (size_t)NE * DH;
  bf16* Q  = Hb + (size_t)NE * DH;
  unsigned short* Vb16 = (unsigned short*)Hb;  // dead before fusedmp1 writes Hb
  bf16* Hrev = Hb;                             // iter2 out (Hb dead after gemmq2)
  unsigned short* Et   = (unsigned short*)Q;   // dead after h0
  unsigned short* Abuf = (unsigned short*)Q;   // alive after fusedmp2
  int* counts   = (int*)(Q + (size_t)NE * DH);
  int* chunkSum = counts + NN;
  int* chunkOff = chunkSum + 1024;
  int* offsets  = chunkOff + 1024;
  int* cursor   = offsets + NN + 1;
  int* perm     = cursor + NN;
  int* ipos     = perm + NE;
  int* rpos     = ipos + NE;
  int* psrc     = rpos + NE;
  unsigned short* Bpi = (unsigned short*)(((uintptr_t)(psrc + NE) + 15) & ~(uintptr_t)15);
  unsigned short* Bph = Bpi + (size_t)CI * 832 * 8;
  unsigned short* Bpo = Bph + (size_t)CH * 832 * 8;

  const int gGE = NE / MT;                 // 3125
  const int gON = (NN + MT - 1) / MT;      // 1563
  const int gE  = (NE + 255) / 256;        // 1563
  const int gN  = (NN + 255) / 256;        // 782
  const int gG  = (NN * 25 + 255) / 256;   // 19532

  // ---- CSR build (by dst; out-edges of n are in-edges ^1) ----
  hipMemsetAsync(counts, 0, (size_t)NN * sizeof(int), stream);
  hist_kernel<<<gE, 256, 0, stream>>>(dst, counts);
  chunksum_kernel<<<NCH, 256, 0, stream>>>(counts, chunkSum);
  scanchunks_kernel<<<1, 1024, 0, stream>>>(chunkSum, chunkOff);
  scanlocal_kernel<<<gN, 256, 0, stream>>>(counts, chunkOff, offsets, cursor);
  scatter_kernel<<<gE, 256, 0, stream>>>(dst, cursor, perm);
  invperm_kernel<<<gE, 256, 0, stream>>>(perm, ipos);
  rpos_kernel<<<gE, 256, 0, stream>>>(perm, ipos, src, rpos, psrc);

  // ---- packed weights (MFMA fragment order, bf16, zero-padded) ----
  prepwpack_kernel<<<(CI * 832 + 255) / 256, 256, 0, stream>>>(Wi, DV + DE, CI, 0, Bpi);
  prepwpack_kernel<<<(CH * 832 + 255) / 256, 256, 0, stream>>>(Wh, DH, CH, 0, Bph);
  prepwpack_kernel<<<(CO * 832 + 255) / 256, 256, 0, stream>>>(Wo, 0, CO, 1, Bpo);

  // ---- V -> bf16 (into Vb16, aliases Hb; dead before fusedmp1 writes Hb) ----
  packv_kernel<<<(NN * (LDV / 8) + 255) / 256, 256, 0, stream>>>(V, Vb16);
  // ---- per-position tail (aliases Q; dead before gemmq1 writes Q) ----
  packet_kernel<<<(NE * 4 + 255) / 256, 256, 0, stream>>>(V, Ef, perm, psrc, Et);

  // ---- H0p (perm-ordered) ----
  h0_kernel<<<gGE, 256, 0, stream>>>(Vb16, Et, psrc, Bpi, bi, H0);

  // iter 1: Q = H0p@Wh; Hbp[rp] = relu(H0p[rp] + a_n - Qp[p])
  gemmq_kernel<<<gGE, 256, 0, stream>>>(H0, Bph, Q);
  fusedmp_kernel<<<gG, 256, 0, stream>>>(Q, H0, offsets, rpos, bh, 0, Hb);

  // iter 2: Q = Hbp@Wh; Hrev[p] = relu(H0p[rp] + a_n - Qp[p])  (seq write)
  gemmq_kernel<<<gGE, 256, 0, stream>>>(Hb, Bph, Q);
  fusedmp_kernel<<<gG, 256, 0, stream>>>(Q, H0, offsets, rpos, bh, 1, Hrev);

  // Q dead now: fill Abuf(=Q) V-columns + padding
  packav_kernel<<<(NNPAD * (KO / 8) + 255) / 256, 256, 0, stream>>>(V, Abuf);

  // readout: Mv[n] = sum_{p in seg(n)} Hrev[p]  (fully sequential)
  gatherseq_kernel<<<gG, 256, 0, stream>>>(Hrev, offsets, Abuf);
  out_kernel<<<gON, 256, 0, stream>>>(Abuf, Bpo, bo, (float*)d_out);
}